// Round 6
// baseline (243.888 us; speedup 1.0000x reference)
//
#include <hip/hip_runtime.h>
#include <math.h>

// Problem constants
#define B_    32
#define S_    2048
#define CIN_  256
#define COUT_ 256
#define K_    16
#define TOUT_ 2033   // S - K + 1

typedef __bf16 bf16x4 __attribute__((ext_vector_type(4)));
typedef __bf16 bf16x8 __attribute__((ext_vector_type(8)));
typedef float  f32x16 __attribute__((ext_vector_type(16)));

// ---------------------------------------------------------------------------
// Build w_eff as the R4-verified fragment-major blob for v_mfma_f32_32x32x16.
// Element (o, i, kk), chunk c = kk*8 + (i>>5):
//   ob = o>>5, s = (i>>4)&1, kh = (i>>3)&1, olow = o&31, j = i&7
//   addr = ((c*8 + ob)*4 + s*2 + kh)*256 + olow*8 + j           [2 MB total]
// B-frag for (c, ob, s): lane L reads 16 B at ((c*8+ob)*4 + s*2)*256 + L*8
// -> fully-coalesced 1 KB per wave-fragment, direct global->register.
// ---------------------------------------------------------------------------
__global__ void __launch_bounds__(256) build_wt_kernel(const float* __restrict__ wr,
                                                       const float* __restrict__ wi,
                                                       const float* __restrict__ ph,
                                                       __bf16* __restrict__ wt) {
  int t = blockIdx.x * 256 + threadIdx.x;   // one thread per (o,i)
  int o = t >> 8, i = t & 255;
  const float4* wr4 = (const float4*)(wr + (size_t)(o * CIN_ + i) * K_);
  const float4* wi4 = (const float4*)(wi + (size_t)(o * CIN_ + i) * K_);
  float re[16], im[16];
  #pragma unroll
  for (int v = 0; v < 4; v++) {
    float4 a = wr4[v];
    re[4*v+0]=a.x; re[4*v+1]=a.y; re[4*v+2]=a.z; re[4*v+3]=a.w;
    float4 b = wi4[v];
    im[4*v+0]=b.x; im[4*v+1]=b.y; im[4*v+2]=b.z; im[4*v+3]=b.w;
  }
  const int ob = o >> 5, s = (i >> 4) & 1, kh = (i >> 3) & 1;
  const int olow = o & 31, j = i & 7;
  const int ic = i >> 5;
  #pragma unroll
  for (int kk = 0; kk < K_; kk++) {
    float p = ph[kk];
    int c = kk * 8 + ic;
    int addr = (((c * 8 + ob) * 4 + s * 2 + kh) * 256) + olow * 8 + j;
    wt[addr] = (__bf16)(cosf(p)*re[kk] - sinf(p)*im[kk]);
  }
}

// ---------------------------------------------------------------------------
// Main: implicit-GEMM conv, 32x32x16 bf16 MFMA, single-barrier kernel.
// Block = 256 threads (4 waves, 2x2), C-tile 128x128 (t x o),
// wave tile 64x64 = 2x2 of 32x32, BK=32 -> 8 MFMAs/interval.
// A: ENTIRE panel x[t0..t0+143][0..256) staged once as bf16 in plane-major
//    LDS [32 planes][145 rows][8] (74.2 KB; plane = ic*4 + s*2 + lhi), the
//    R4-verified fragment layout -> conflict-free lane-sequential reads.
// K-loop: barrier-free; A-frags (ds_read_b128) and B-frags (global 16 B/lane,
//    L2-resident blob) both register-double-buffered one interval ahead ->
//    loop waits are vmcnt(4)/lgkmcnt(4) on interval-old loads (AITER-style).
// ---------------------------------------------------------------------------
#define PR 145  // padded rows per plane

__global__ void __launch_bounds__(256) conv_mfma_kernel(const float* __restrict__ xg,
                                                        const __bf16* __restrict__ wt,
                                                        float* __restrict__ out) {
  __shared__ __align__(16) __bf16 As[32 * PR * 8];  // 74240 B

  const int bx = blockIdx.x;
  const int nb = bx & 1;          // o-block 0..1
  const int mb = (bx >> 1) & 15;  // t-block 0..15
  const int b  = bx >> 5;         // batch   0..31

  const int tid  = threadIdx.x;
  const int w    = tid >> 6;
  const int lane = tid & 63;
  const int wm   = w >> 1, wn = w & 1;
  const int l31  = lane & 31, lhi = lane >> 5;

  const int t0 = mb * 128;
  const int o0 = nb * 128;

  const float* xbase = xg + (size_t)b * (S_ * CIN_);

  // ---- Prologue: stage full A panel (144 rows x 256 ch), bf16, plane-major
  {
    const int sr  = tid >> 3;        // 0..31
    const int sc4 = (tid & 7) * 4;   // 0,4,...,28 within a 32-ch group
    const int spl = sc4 >> 3;        // sub-plane 0..3
    const int sj  = sc4 & 7;         // 0 or 4
    for (int ic = 0; ic < 8; ++ic) {
      const float* xcol = xbase + ic * 32 + sc4;
      __bf16* dst = As + ((ic * 4 + spl) * PR) * 8 + sj;
      #pragma unroll
      for (int p = 0; p < 4; p++) {
        int r = p * 32 + sr;
        int rg = t0 + r; rg = (rg < S_) ? rg : (S_ - 1);
        float4 v = *(const float4*)(xcol + (size_t)rg * CIN_);
        bf16x4 o4; o4[0]=(__bf16)v.x; o4[1]=(__bf16)v.y; o4[2]=(__bf16)v.z; o4[3]=(__bf16)v.w;
        *(bf16x4*)(dst + r * 8) = o4;
      }
      if (tid < 128) {  // tail rows 128..143
        int r = 128 + sr;
        int rg = t0 + r; rg = (rg < S_) ? rg : (S_ - 1);
        float4 v = *(const float4*)(xcol + (size_t)rg * CIN_);
        bf16x4 o4; o4[0]=(__bf16)v.x; o4[1]=(__bf16)v.y; o4[2]=(__bf16)v.z; o4[3]=(__bf16)v.w;
        *(bf16x4*)(dst + r * 8) = o4;
      }
    }
  }
  __syncthreads();  // the ONLY barrier

  // B fragment bases (o-tiles ob = nb*4 + wn*2 + jn), + c*8192 + s*512 per frag
  const __bf16* bptr[2] = {
    wt + (size_t)nb * 4096 + (wn * 2 + 0) * 1024 + lane * 8,
    wt + (size_t)nb * 4096 + (wn * 2 + 1) * 1024 + lane * 8
  };
  const int arow = wm * 64 + l31;  // + kk + jm*32 per frag

  auto load_a = [&](int g, bf16x8 (&af)[2][2]) {
    int ic = g >> 4, kk = g & 15;
    #pragma unroll
    for (int jm = 0; jm < 2; jm++)
      #pragma unroll
      for (int s = 0; s < 2; s++) {
        int plane = ic * 4 + s * 2 + lhi;
        af[jm][s] = *(const bf16x8*)(As + (plane * PR + kk + arow + jm * 32) * 8);
      }
  };
  auto load_b = [&](int g, bf16x8 (&bf)[2][2]) {
    size_t co = (size_t)(((g & 15) << 3) + (g >> 4)) * 8192;
    #pragma unroll
    for (int jn = 0; jn < 2; jn++)
      #pragma unroll
      for (int s = 0; s < 2; s++)
        bf[jn][s] = *(const bf16x8*)(bptr[jn] + co + s * 512);
  };

  f32x16 acc[2][2];
  #pragma unroll
  for (int jm = 0; jm < 2; jm++)
    #pragma unroll
    for (int jn = 0; jn < 2; jn++)
      #pragma unroll
      for (int r = 0; r < 16; r++)
        acc[jm][jn][r] = 0.f;

  bf16x8 ab[2][2][2], bb[2][2][2];
  load_a(0, ab[0]);
  load_b(0, bb[0]);

  #pragma unroll 2
  for (int g = 0; g < 128; ++g) {
    const int cur = g & 1, nxt = cur ^ 1;
    const int gn = (g < 127) ? g + 1 : 127;
    load_a(gn, ab[nxt]);   // 4 ds_read_b128, consumed next interval
    load_b(gn, bb[nxt]);   // 4 global dwordx4 (L2-hot), consumed next interval
    #pragma unroll
    for (int s = 0; s < 2; s++)
      #pragma unroll
      for (int jm = 0; jm < 2; jm++)
        #pragma unroll
        for (int jn = 0; jn < 2; jn++)
          acc[jm][jn] = __builtin_amdgcn_mfma_f32_32x32x16_bf16(
              ab[cur][jm][s], bb[cur][jn][s], acc[jm][jn], 0, 0, 0);
  }

  // ---- Epilogue (R4-verified): col = l31, row = (reg&3) + 8*(reg>>2) + 4*lhi
  float* obase = out + (size_t)b * TOUT_ * COUT_;
  #pragma unroll
  for (int jm = 0; jm < 2; jm++) {
    #pragma unroll
    for (int reg = 0; reg < 16; reg++) {
      int rowcd = (reg & 3) + 8 * (reg >> 2) + 4 * lhi;
      int t = t0 + wm * 64 + jm * 32 + rowcd;
      if (t < TOUT_) {
        float* orow = obase + (size_t)t * COUT_ + o0 + wn * 64 + l31;
        orow[0]  = acc[jm][0][reg];
        orow[32] = acc[jm][1][reg];
      }
    }
  }
}

// ---------------------------------------------------------------------------
extern "C" void kernel_launch(void* const* d_in, const int* in_sizes, int n_in,
                              void* d_out, int out_size, void* d_ws, size_t ws_size,
                              hipStream_t stream) {
  const float* x  = (const float*)d_in[0];
  const float* wr = (const float*)d_in[1];
  const float* wi = (const float*)d_in[2];
  const float* ph = (const float*)d_in[3];
  float* out = (float*)d_out;

  __bf16* wt = (__bf16*)d_ws;  // 2 MB only

  build_wt_kernel<<<dim3((COUT_ * CIN_) / 256), dim3(256), 0, stream>>>(wr, wi, ph, wt);
  conv_mfma_kernel<<<dim3(B_ * 16 * 2), dim3(256), 0, stream>>>(x, wt, out);
}